// Round 10
// baseline (146.158 us; speedup 1.0000x reference)
//
#include <hip/hip_runtime.h>

typedef _Float16 half_t;
typedef __fp16   fp16x2 __attribute__((ext_vector_type(2)));
typedef _Float16 half4_t __attribute__((ext_vector_type(4)));
typedef _Float16 half8   __attribute__((ext_vector_type(8)));
typedef float    f32x4   __attribute__((ext_vector_type(4)));
typedef unsigned short u16x8 __attribute__((ext_vector_type(8)));

#define KP_S    0.057735026918962574f  // 0.1/sqrt(3)
#define INV_EXT 11.547005383792515f    // 1/(0.05*sqrt(3))
#define GPITCH  3584                   // G bytes/query: 64*28*2; banking via XOR swizzle
#define NBLK    256                    // persistent blocks = 1/CU exactly (1024 thr)
#define NTILE   1250                   // 40000 queries / 32 per tile

union H8 { half8 v; fp16x2 h2[4]; };
union H4 { half4_t v; fp16x2 h2[2]; };

// WT[o][k], k = i*28 + l (fp16); l==27 zero pad mirrors G's pitch-28 layout.
// Channel permutation c = 4*(i&15) + (i>>4): MFMA column (nt,lr) holds x-channel
// 4*lr+nt so the phase-C gather is a single float4 per lane per row.
__global__ void build_wt(const float* __restrict__ W, half_t* __restrict__ WT) {
    int t = blockIdx.x * 256 + threadIdx.x;       // 64*1792 = 114688 exact
    if (t >= 64 * 1792) return;
    int o = t / 1792, k = t - o * 1792;
    int i = k / 28,   l = k - i * 28;
    int c = 4 * (i & 15) + (i >> 4);              // permuted channel index
    WT[t] = (l < 27) ? (half_t)W[(l * 64 + c) * 64 + o] : (half_t)0.f;
}

// issue one query's x-gather: 8 coalesced nontemporal float4 loads
#define ISSUE_XV1(BUF, Q, XV) do {                                             \
    u16x8 id8 = *(const u16x8*)&idx_lds[BUF][Q][8 * g];                        \
    _Pragma("unroll")                                                          \
    for (int j = 0; j < 8; ++j)                                                \
        XV[j] = __builtin_nontemporal_load(                                    \
                    (const f32x4*)(x + (int)id8[j] * 64 + 4 * lr));            \
} while (0)

// pack 8 float4 -> 4 half8 B-fragments; B-frag nt takes vector element nt
#define PACK_B(XV, BF) do {                                                    \
    _Pragma("unroll")                                                          \
    for (int nt = 0; nt < 4; ++nt) {                                           \
        _Pragma("unroll")                                                      \
        for (int p = 0; p < 4; ++p)                                            \
            BF[nt].h2[p] = __builtin_amdgcn_cvt_pkrtz(XV[2 * p][nt],           \
                                                      XV[2 * p + 1][nt]);      \
    }                                                                          \
} while (0)

// per-lane influence weights + stage-1 MFMAs + XOR-swizzled G dump for one query
#define MFMA_DUMP(Q, CUR, BF) do {                                             \
    float w0v[8], w1v[8];                                                      \
    _Pragma("unroll")                                                          \
    for (int j = 0; j < 8; ++j) {                                              \
        half4_t nb = nbr_lds[CUR][Q][8 * g + j];                               \
        float nx = (float)nb[0], ny = (float)nb[1], nz = (float)nb[2];         \
        float dx = nx - kx0, dy = ny - ky0, dz = nz - kz0;                     \
        w0v[j] = fmaxf(fmaf(__builtin_amdgcn_sqrtf(dx*dx + dy*dy + dz*dz), -INV_EXT, 1.f), 0.f); \
        float ex = nx - kx1, ey = ny - ky1, ez = nz - kz1;                     \
        w1v[j] = fmaxf(fmaf(__builtin_amdgcn_sqrtf(ex*ex + ey*ey + ez*ez), -INV_EXT, cbias), 0.f); \
    }                                                                          \
    H8 A0, A1;                                                                 \
    _Pragma("unroll")                                                          \
    for (int p = 0; p < 4; ++p) {                                              \
        A0.h2[p] = __builtin_amdgcn_cvt_pkrtz(w0v[2*p], w0v[2*p+1]);           \
        A1.h2[p] = __builtin_amdgcn_cvt_pkrtz(w1v[2*p], w1v[2*p+1]);           \
    }                                                                          \
    char* gq = g_mem + (Q) * GPITCH;                                           \
    const int xq = ((Q) & 7) << 4;                                             \
    _Pragma("unroll")                                                          \
    for (int nt = 0; nt < 4; ++nt) {                                           \
        f32x4 z = {0.f, 0.f, 0.f, 0.f};                                        \
        f32x4 c0 = __builtin_amdgcn_mfma_f32_16x16x32_f16(A0.v, BF[nt].v, z, 0, 0, 0); \
        f32x4 c1 = __builtin_amdgcn_mfma_f32_16x16x32_f16(A1.v, BF[nt].v, z, 0, 0, 0); \
        const int ic = 16 * nt + lr;                                           \
        H4 h0;                                                                 \
        h0.h2[0] = __builtin_amdgcn_cvt_pkrtz(c0[0], c0[1]);                   \
        h0.h2[1] = __builtin_amdgcn_cvt_pkrtz(c0[2], c0[3]);                   \
        *(half4_t*)(gq + ((2 * (ic * 28 + 4 * g)) ^ xq)) = h0.v;               \
        if (4 * g < 12) {                                                      \
            H4 h1;                                                             \
            h1.h2[0] = __builtin_amdgcn_cvt_pkrtz(c1[0], c1[1]);               \
            h1.h2[1] = __builtin_amdgcn_cvt_pkrtz(c1[2], c1[3]);               \
            *(half4_t*)(gq + ((2 * (ic * 28 + 16 + 4 * g)) ^ xq)) = h1.v;      \
        }                                                                      \
    }                                                                          \
} while (0)

#define BODY(T, TN, CUR) do {                                                  \
    /* qB gather for current tile (consumed after qA's dump) */                \
    f32x4 xvB[8];                                                              \
    ISSUE_XV1(CUR, 2 * wid + 1, xvB);                                          \
    /* next-tile phase A chain: inds -> s_pts/q_pts -> regs */                 \
    const int nn   = (TN) * 32 + aq;                                           \
    const int idxN = inds[nn * 32 + ah];                                       \
    const float sx = s_pts[idxN * 3 + 0] - q_pts[nn * 3 + 0];                  \
    const float sy = s_pts[idxN * 3 + 1] - q_pts[nn * 3 + 1];                  \
    const float sz = s_pts[idxN * 3 + 2] - q_pts[nn * 3 + 2];                  \
    /* phase C: 2 queries per wave */                                          \
    H8 BFA[4];                                                                 \
    PACK_B(xv, BFA);                                                           \
    MFMA_DUMP(2 * wid, CUR, BFA);                                              \
    H8 BFB[4];                                                                 \
    PACK_B(xvB, BFB);                                                          \
    MFMA_DUMP(2 * wid + 1, CUR, BFB);                                          \
    idx_lds[(CUR) ^ 1][aq][ah] = (unsigned short)idxN;                         \
    { H4 nv;                                                                   \
      nv.h2[0] = __builtin_amdgcn_cvt_pkrtz(sx, sy);                           \
      nv.h2[1] = __builtin_amdgcn_cvt_pkrtz(sz, 0.f);                          \
      nbr_lds[(CUR) ^ 1][aq][ah] = nv.v; }                                     \
    __syncthreads();                                                           \
    /* refill qA gather for next tile under phase D */                         \
    ISSUE_XV1((CUR) ^ 1, 2 * wid, xv);                                         \
    /* phase D: fx[32,64] = G[32,1792] @ WT^T; wave=(ot,kh); 2 M=16 passes     \
       share every WT load; K split 4-way across kh */                         \
    const half_t* wrow = WT + (16 * ot + lr) * 1792 + kh * 448 + 8 * g;        \
    const char* gb0 = g_mem + lr * GPITCH;                                     \
    const char* gb1 = g_mem + (16 + lr) * GPITCH;                              \
    const int koff = 896 * kh + 16 * g;                                        \
    const int xr   = (lr & 7) << 4;                                            \
    f32x4 acc0 = {0.f, 0.f, 0.f, 0.f}, acc1 = {0.f, 0.f, 0.f, 0.f};            \
    _Pragma("unroll")                                                          \
    for (int s = 0; s < 14; ++s) {                                             \
        half8 bA = *(const half8*)(wrow + 32 * s);                             \
        half8 a0 = *(const half8*)(gb0 + ((koff + 64 * s) ^ xr));              \
        half8 a1 = *(const half8*)(gb1 + ((koff + 64 * s) ^ xr));              \
        acc0 = __builtin_amdgcn_mfma_f32_16x16x32_f16(a0, bA, acc0, 0, 0, 0);  \
        acc1 = __builtin_amdgcn_mfma_f32_16x16x32_f16(a1, bA, acc1, 0, 0, 0);  \
    }                                                                          \
    if (kh) { red[0][kh - 1][ot][lane] = acc0;                                 \
              red[1][kh - 1][ot][lane] = acc1; }                               \
    __syncthreads();                                                           \
    if (!kh) {                                                                 \
        f32x4 r0 = acc0 + red[0][0][ot][lane] + red[0][1][ot][lane] + red[0][2][ot][lane]; \
        f32x4 r1 = acc1 + red[1][0][ot][lane] + red[1][1][ot][lane] + red[1][2][ot][lane]; \
        const int o = 16 * ot + lr;                                            \
        _Pragma("unroll")                                                      \
        for (int r = 0; r < 4; ++r) {                                          \
            out[((T) * 32 + 4 * g + r) * 64 + o]      = r0[r];                 \
            out[((T) * 32 + 16 + 4 * g + r) * 64 + o] = r1[r];                 \
        }                                                                      \
    }                                                                          \
} while (0)

__global__ __launch_bounds__(1024, 4) void kpconv(
    const float* __restrict__ q_pts, const float* __restrict__ s_pts,
    const int*   __restrict__ inds,  const float* __restrict__ x,
    const half_t* __restrict__ WT,   float* __restrict__ out)
{
    // LDS: 114688 + 4096 + 16384 + 24576 = 159744 B -> 1 block/CU (16 waves)
    __shared__ __align__(16) char    g_mem[32 * GPITCH];          // G[q][i*28+l] fp16, XOR-swz
    __shared__ __align__(16) unsigned short idx_lds[2][32][32];   // double-buffered
    __shared__ __align__(16) half4_t nbr_lds[2][32][32];          // double-buffered fp16
    __shared__ __align__(16) f32x4   red[2][3][4][64];            // phase-D K-reduction

    const int tid  = threadIdx.x;
    const int lane = tid & 63, wid = tid >> 6;      // wid 0..15
    const int lr   = lane & 15, g = lane >> 4;
    const int aq   = tid >> 5,  ah = tid & 31;      // phase-A mapping: 32q x 32h
    const int ot   = wid & 3,   kh = wid >> 2;      // phase-D wave role (4 ot x 4 kh)

    // this lane's two kernel points: l0 = lr (always valid), l1 = lr+16 (>=27 -> w=0)
    const float kx0 = (float)((lr / 3) % 3 - 1) * KP_S;
    const float ky0 = (float)( lr / 9      - 1) * KP_S;
    const float kz0 = (float)( lr % 3      - 1) * KP_S;
    const int   l1  = lr + 16;
    const float kx1 = (float)((l1 / 3) % 3 - 1) * KP_S;
    const float ky1 = (float)( l1 / 9      - 1) * KP_S;
    const float kz1 = (float)( l1 % 3      - 1) * KP_S;
    const float cbias = (l1 < 27) ? 1.f : -1.f;     // forces w1=0 for pad rows

    // ---- prologue: phase A for first tile -> buffer 0 ----
    {
        int n   = blockIdx.x * 32 + aq;
        int idx = inds[n * 32 + ah];
        idx_lds[0][aq][ah] = (unsigned short)idx;
        float dx = s_pts[idx * 3 + 0] - q_pts[n * 3 + 0];
        float dy = s_pts[idx * 3 + 1] - q_pts[n * 3 + 1];
        float dz = s_pts[idx * 3 + 2] - q_pts[n * 3 + 2];
        H4 nv;
        nv.h2[0] = __builtin_amdgcn_cvt_pkrtz(dx, dy);
        nv.h2[1] = __builtin_amdgcn_cvt_pkrtz(dz, 0.f);
        nbr_lds[0][aq][ah] = nv.v;
    }
    __syncthreads();

    f32x4 xv[8];
    ISSUE_XV1(0, 2 * wid, xv);

    int cur = 0;
    for (int t = blockIdx.x; t < NTILE; t += NBLK) {
        int tn = (t + NBLK < NTILE) ? t + NBLK : t;   // clamp: last iter re-fetches self
        BODY(t, tn, cur);
        cur ^= 1;
    }
}

extern "C" void kernel_launch(void* const* d_in, const int* in_sizes, int n_in,
                              void* d_out, int out_size, void* d_ws, size_t ws_size,
                              hipStream_t stream) {
    const float* q_pts = (const float*)d_in[0];
    const float* s_pts = (const float*)d_in[1];
    const int*   inds  = (const int*)d_in[2];
    const float* x     = (const float*)d_in[3];
    const float* W     = (const float*)d_in[4];
    float* out = (float*)d_out;
    half_t* WT = (half_t*)d_ws;                 // 64*1792*2 = 229376 B

    build_wt<<<448, 256, 0, stream>>>(W, WT);   // 448*256 = 114688 exact
    kpconv<<<NBLK, 1024, 0, stream>>>(q_pts, s_pts, inds, x, WT, out);
}

// Round 11
// 97.234 us; speedup vs baseline: 1.5032x; 1.5032x over previous
//
#include <hip/hip_runtime.h>

typedef _Float16 half_t;
typedef __fp16   fp16x2 __attribute__((ext_vector_type(2)));
typedef _Float16 half4_t __attribute__((ext_vector_type(4)));
typedef _Float16 half8   __attribute__((ext_vector_type(8)));
typedef float    f32x4   __attribute__((ext_vector_type(4)));
typedef unsigned short u16x8 __attribute__((ext_vector_type(8)));

#define KP_S    0.057735026918962574f  // 0.1/sqrt(3)
#define INV_EXT 11.547005383792515f    // 1/(0.05*sqrt(3))
#define GPITCH  3616                   // G bytes/query: 64*28*2 data + 32 pad
#define NBLK    512                    // persistent blocks = 2/CU exactly
#define NTILE   2500                   // 40000 queries / 16 per tile
#define WT_BYTES (64 * 1792 * 2)       // 229376
#define XH_BYTES (40000 * 64 * 2)      // 5120000

union H8 { half8 v; fp16x2 h2[4]; };
union H4 { half4_t v; fp16x2 h2[2]; };

// WT[o][k], k = i*28 + l (fp16); l==27 zero pad mirrors G's pitch-28 pad.
// Channel permutation c = 4*(i&15) + (i>>4): MFMA column (nt,lr) holds x-channel
// 4*lr+nt so the phase-C gather is one 8B (fp16) load per lane per row.
__global__ void build_wt(const float* __restrict__ W, half_t* __restrict__ WT) {
    int t = blockIdx.x * 256 + threadIdx.x;       // 64*1792 = 114688 exact
    if (t >= 64 * 1792) return;
    int o = t / 1792, k = t - o * 1792;
    int i = k / 28,   l = k - i * 28;
    int c = 4 * (i & 15) + (i >> 4);              // permuted channel index
    WT[t] = (l < 27) ? (half_t)W[(l * 64 + c) * 64 + o] : (half_t)0.f;
}

// x (f32, [40000][64]) -> xh (fp16, same layout): 128 B/row = 1 cache line
__global__ void build_xh(const float* __restrict__ x, half_t* __restrict__ xh) {
    int t = blockIdx.x * 256 + threadIdx.x;       // 2500*256 = 640000 exact
    f32x4 v = *(const f32x4*)(x + t * 4);
    H4 h;
    h.h2[0] = __builtin_amdgcn_cvt_pkrtz(v.x, v.y);
    h.h2[1] = __builtin_amdgcn_cvt_pkrtz(v.z, v.w);
    *(half4_t*)(xh + t * 4) = h.v;
}

// issue one query's x-gather into 8 half4 regs (16 VGPR)
#define ISSUE_XV1(BUF, Q, XV) do {                                             \
    u16x8 id8 = *(const u16x8*)&idx_lds[BUF][Q][8 * g];                        \
    _Pragma("unroll")                                                          \
    for (int j = 0; j < 8; ++j) {                                              \
        if constexpr (XHALF) {                                                 \
            XV[j] = *(const half4_t*)(xh + (int)id8[j] * 64 + 4 * lr);         \
        } else {                                                               \
            f32x4 t4 = *(const f32x4*)(x + (int)id8[j] * 64 + 4 * lr);         \
            H4 hh;                                                             \
            hh.h2[0] = __builtin_amdgcn_cvt_pkrtz(t4.x, t4.y);                 \
            hh.h2[1] = __builtin_amdgcn_cvt_pkrtz(t4.z, t4.w);                 \
            XV[j] = hh.v;                                                      \
        }                                                                      \
    }                                                                          \
} while (0)

// transpose 8 half4 -> 4 half8 B-fragments (pure fp16 lane-local shuffles)
#define PACK_B(XV, BF) do {                                                    \
    _Pragma("unroll")                                                          \
    for (int nt = 0; nt < 4; ++nt) {                                           \
        half8 b;                                                               \
        _Pragma("unroll")                                                      \
        for (int j = 0; j < 8; ++j) b[j] = XV[j][nt];                          \
        BF[nt].v = b;                                                          \
    }                                                                          \
} while (0)

// per-lane influence weights + stage-1 MFMAs + G dump for one query
#define MFMA_DUMP(Q, CUR, BF) do {                                             \
    float w0v[8], w1v[8];                                                      \
    _Pragma("unroll")                                                          \
    for (int j = 0; j < 8; ++j) {                                              \
        f32x4 nb = nbr_lds[CUR][Q][8 * g + j];                                 \
        float dx = nb.x - kx0, dy = nb.y - ky0, dz = nb.z - kz0;               \
        w0v[j] = fmaxf(fmaf(__builtin_amdgcn_sqrtf(dx*dx + dy*dy + dz*dz), -INV_EXT, 1.f), 0.f); \
        float ex = nb.x - kx1, ey = nb.y - ky1, ez = nb.z - kz1;               \
        w1v[j] = fmaxf(fmaf(__builtin_amdgcn_sqrtf(ex*ex + ey*ey + ez*ez), -INV_EXT, cbias), 0.f); \
    }                                                                          \
    H8 A0, A1;                                                                 \
    _Pragma("unroll")                                                          \
    for (int p = 0; p < 4; ++p) {                                              \
        A0.h2[p] = __builtin_amdgcn_cvt_pkrtz(w0v[2*p], w0v[2*p+1]);           \
        A1.h2[p] = __builtin_amdgcn_cvt_pkrtz(w1v[2*p], w1v[2*p+1]);           \
    }                                                                          \
    char* gq = g_mem + (Q) * GPITCH;                                           \
    _Pragma("unroll")                                                          \
    for (int nt = 0; nt < 4; ++nt) {                                           \
        f32x4 z = {0.f, 0.f, 0.f, 0.f};                                        \
        f32x4 c0 = __builtin_amdgcn_mfma_f32_16x16x32_f16(A0.v, BF[nt].v, z, 0, 0, 0); \
        f32x4 c1 = __builtin_amdgcn_mfma_f32_16x16x32_f16(A1.v, BF[nt].v, z, 0, 0, 0); \
        const int ic = 16 * nt + lr;                                           \
        H4 h0;                                                                 \
        h0.h2[0] = __builtin_amdgcn_cvt_pkrtz(c0[0], c0[1]);                   \
        h0.h2[1] = __builtin_amdgcn_cvt_pkrtz(c0[2], c0[3]);                   \
        *(half4_t*)(gq + 2 * (ic * 28 + 4 * g)) = h0.v;                        \
        if (4 * g < 12) {                                                      \
            H4 h1;                                                             \
            h1.h2[0] = __builtin_amdgcn_cvt_pkrtz(c1[0], c1[1]);               \
            h1.h2[1] = __builtin_amdgcn_cvt_pkrtz(c1[2], c1[3]);               \
            *(half4_t*)(gq + 2 * (ic * 28 + 16 + 4 * g)) = h1.v;               \
        }                                                                      \
    }                                                                          \
} while (0)

#define BODY(T, TN, CUR, XV) do {                                              \
    /* issue qB gather first (8 loads in flight across qA compute) */          \
    half4_t xvB[8];                                                            \
    ISSUE_XV1(CUR, 2 * wid + 1, xvB);                                          \
    H8 BFA[4];                                                                 \
    PACK_B(XV, BFA);                                                           \
    const int nn   = (TN) * 16 + aq;                                           \
    const int idxN = inds[nn * 32 + ah];                                       \
    MFMA_DUMP(2 * wid, CUR, BFA);                                              \
    f32x4 vN;                                                                  \
    vN.x = s_pts[idxN * 3 + 0] - q_pts[nn * 3 + 0];                            \
    vN.y = s_pts[idxN * 3 + 1] - q_pts[nn * 3 + 1];                            \
    vN.z = s_pts[idxN * 3 + 2] - q_pts[nn * 3 + 2];                            \
    vN.w = 0.f;                                                                \
    H8 BFB[4];                                                                 \
    PACK_B(xvB, BFB);                                                          \
    MFMA_DUMP(2 * wid + 1, CUR, BFB);                                          \
    idx_lds[(CUR) ^ 1][aq][ah] = (unsigned short)idxN;                         \
    nbr_lds[(CUR) ^ 1][aq][ah] = vN;                                           \
    __syncthreads();                                                           \
    /* refill XV with next tile's qA under phase D */                          \
    ISSUE_XV1((CUR) ^ 1, 2 * wid, XV);                                         \
    /* phase D for T: fx[16,64] = G @ WT^T, wave = (o-tile, K-half) */         \
    const half_t* wrow = WT + (16 * ot + lr) * 1792 + kh * 896 + 8 * g;        \
    const char*   gb   = g_mem + lr * GPITCH + kh * 1792;                      \
    f32x4 accA = {0.f, 0.f, 0.f, 0.f}, accB = {0.f, 0.f, 0.f, 0.f};            \
    _Pragma("unroll 7")                                                        \
    for (int s = 0; s < 28; s += 2) {                                          \
        half8 aA = *(const half8*)(gb + 64 * s + 16 * g);                      \
        half8 bA = *(const half8*)(wrow + 32 * s);                             \
        accA = __builtin_amdgcn_mfma_f32_16x16x32_f16(aA, bA, accA, 0, 0, 0);  \
        half8 aB = *(const half8*)(gb + 64 * (s + 1) + 16 * g);                \
        half8 bB = *(const half8*)(wrow + 32 * (s + 1));                       \
        accB = __builtin_amdgcn_mfma_f32_16x16x32_f16(aB, bB, accB, 0, 0, 0);  \
    }                                                                          \
    f32x4 acc = accA + accB;                                                   \
    if (kh) *(f32x4*)&red[ot][lane] = acc;                                     \
    __syncthreads();                                                           \
    if (!kh) {                                                                 \
        f32x4 p = red[ot][lane];                                               \
        const int o = 16 * ot + lr;                                            \
        _Pragma("unroll")                                                      \
        for (int r = 0; r < 4; ++r)                                            \
            out[((T) * 16 + 4 * g + r) * 64 + o] = acc[r] + p[r];              \
    }                                                                          \
} while (0)

template <int XHALF>
__global__ __launch_bounds__(512, 4) void kpconv(
    const float* __restrict__ q_pts, const float* __restrict__ s_pts,
    const int*   __restrict__ inds,  const float* __restrict__ x,
    const half_t* __restrict__ xh,   const half_t* __restrict__ WT,
    float* __restrict__ out)
{
    // LDS: 57856 + 2048 + 16384 + 4096 = 80384 B -> 2 blocks/CU (16 waves/CU)
    __shared__ __align__(16) char   g_mem[16 * GPITCH];          // G[q][i*28+l] fp16
    __shared__ __align__(16) unsigned short idx_lds[2][16][32];  // double-buffered
    __shared__ __align__(16) f32x4  nbr_lds[2][16][32];          // double-buffered
    __shared__ __align__(16) f32x4  red[4][64];                  // phase-D K-reduction

    const int tid  = threadIdx.x;
    const int lane = tid & 63, wid = tid >> 6;
    const int lr   = lane & 15, g = lane >> 4;
    const int aq   = tid >> 5,  ah = tid & 31;      // phase-A mapping: 16q x 32h
    const int ot   = wid & 3,   kh = wid >> 2;      // phase-D wave role

    // this lane's two kernel points: l0 = lr (always valid), l1 = lr+16 (>=27 -> w=0)
    const float kx0 = (float)((lr / 3) % 3 - 1) * KP_S;
    const float ky0 = (float)( lr / 9      - 1) * KP_S;
    const float kz0 = (float)( lr % 3      - 1) * KP_S;
    const int   l1  = lr + 16;
    const float kx1 = (float)((l1 / 3) % 3 - 1) * KP_S;
    const float ky1 = (float)( l1 / 9      - 1) * KP_S;
    const float kz1 = (float)( l1 % 3      - 1) * KP_S;
    const float cbias = (l1 < 27) ? 1.f : -1.f;     // forces w1=0 for pad rows

    // ---- prologue: phase A for first tile -> buffer 0, then issue qA x-gather ----
    {
        int n   = blockIdx.x * 16 + aq;
        int idx = inds[n * 32 + ah];
        idx_lds[0][aq][ah] = (unsigned short)idx;
        f32x4 v;
        v.x = s_pts[idx * 3 + 0] - q_pts[n * 3 + 0];
        v.y = s_pts[idx * 3 + 1] - q_pts[n * 3 + 1];
        v.z = s_pts[idx * 3 + 2] - q_pts[n * 3 + 2];
        v.w = 0.f;
        nbr_lds[0][aq][ah] = v;
    }
    __syncthreads();

    half4_t xv[8];
    ISSUE_XV1(0, 2 * wid, xv);

    int cur = 0;
    for (int t = blockIdx.x; t < NTILE; t += NBLK) {
        int tn = (t + NBLK < NTILE) ? t + NBLK : t;   // clamp: last iter re-fetches self
        BODY(t, tn, cur, xv);
        cur ^= 1;
    }
}

extern "C" void kernel_launch(void* const* d_in, const int* in_sizes, int n_in,
                              void* d_out, int out_size, void* d_ws, size_t ws_size,
                              hipStream_t stream) {
    const float* q_pts = (const float*)d_in[0];
    const float* s_pts = (const float*)d_in[1];
    const int*   inds  = (const int*)d_in[2];
    const float* x     = (const float*)d_in[3];
    const float* W     = (const float*)d_in[4];
    float* out = (float*)d_out;
    half_t* WT = (half_t*)d_ws;                               // 229376 B
    half_t* xh = (half_t*)((char*)d_ws + WT_BYTES);           // 5120000 B

    build_wt<<<448, 256, 0, stream>>>(W, WT);                 // 448*256 = 114688 exact
    if (ws_size >= (size_t)(WT_BYTES + XH_BYTES)) {
        build_xh<<<2500, 256, 0, stream>>>(x, xh);            // 2500*256*4 = 2.56M elems
        kpconv<1><<<NBLK, 512, 0, stream>>>(q_pts, s_pts, inds, x, xh, WT, out);
    } else {
        kpconv<0><<<NBLK, 512, 0, stream>>>(q_pts, s_pts, inds, x, xh, WT, out);
    }
}